// Round 11
// baseline (145.863 us; speedup 1.0000x reference)
//
#include <hip/hip_runtime.h>

typedef __attribute__((ext_vector_type(8))) short short8;
typedef __attribute__((ext_vector_type(16))) float f32x16;
typedef __attribute__((ext_vector_type(4))) unsigned short ushort4v;
typedef __attribute__((ext_vector_type(4))) int int4v;

#define BN_EPS 1e-5f
#define KOFF 27

static __device__ __forceinline__ unsigned short f2bf(float f) {
  unsigned int u = __float_as_uint(f);
  u += 0x7fffu + ((u >> 16) & 1u);
  return (unsigned short)(u >> 16);
}

static __device__ __forceinline__ float silu_f(float z) {
  return z / (1.f + __expf(-z));
}

// ---- fused prep:
// [0, rblk)           : rows[k*N+n] = valid ? idx : N   (nt loads, int4)
// [rblk, rblk+864)    : pack W1+W2 -> bf16 MFMA B-frag order (32x32x16)
// [rblk+864, rblk+872): time MLP
// [rblk+872, ...)     : a1 = bf16(silu(bn1(x))) + zero row N
__global__ void prep_all(int rblk, const int* __restrict__ kidx, const int* __restrict__ kval,
                         int* __restrict__ rows, int N,
                         const float* __restrict__ t, const float* __restrict__ Wt,
                         const float* __restrict__ bt,
                         float* __restrict__ scale_eff, float* __restrict__ shift,
                         const float* __restrict__ W1, const float* __restrict__ W2,
                         unsigned short* __restrict__ Wp1, unsigned short* __restrict__ Wp2,
                         const float* __restrict__ x, const float* __restrict__ g1,
                         const float* __restrict__ b1, const float* __restrict__ m1,
                         const float* __restrict__ v1, unsigned short* __restrict__ a1bf,
                         int total) {
  const int bid = blockIdx.x;
  if (bid < rblk) {
    int i = (bid * 256 + threadIdx.x) * 4;
    if (i < KOFF * N) {
      int4v iv = __builtin_nontemporal_load((const int4v*)(kidx + i));
      int4v vv = __builtin_nontemporal_load((const int4v*)(kval + i));
      int4v r;
      r.x = vv.x ? iv.x : N;
      r.y = vv.y ? iv.y : N;
      r.z = vv.z ? iv.z : N;
      r.w = vv.w ? iv.w : N;
      __builtin_nontemporal_store(r, (int4v*)(rows + i));
    }
  } else if (bid < rblk + 864) {
    int tid = (bid - rblk) * 256 + threadIdx.x;  // 0 .. 221183 = 2*tot
    const int tot = KOFF * 4 * 2 * 64 * 8;
    const float* W = W1;
    unsigned short* Wp = Wp1;
    if (tid >= tot) { tid -= tot; W = W2; Wp = Wp2; }
    int j = tid & 7, lane = (tid >> 3) & 63, cbb = (tid >> 9) & 1,
        ks = (tid >> 10) & 3, k = tid >> 12;
    int ci = ks * 16 + (lane >> 5) * 8 + j;
    int co = cbb * 32 + (lane & 31);
    Wp[tid] = f2bf(W[(k * 64 + ci) * 64 + co]);
  } else if (bid < rblk + 872) {
    int tid = (bid - rblk - 864) * 256 + threadIdx.x;  // 0..2047
    int bi = tid >> 7, co = tid & 127;
    float acc = bt[co];
    for (int e = 0; e < 256; ++e) {
      float tv = t[bi * 256 + e];
      acc += silu_f(tv) * Wt[e * 128 + co];
    }
    if (co < 64) scale_eff[bi * 64 + co] = 1.f + acc;
    else         shift[bi * 64 + (co - 64)] = acc;
  } else {
    int i = ((bid - rblk - 872) * 256 + threadIdx.x) * 4;
    if (i >= total) {
      if (i < total + 64) *(ushort4v*)(a1bf + i) = (ushort4v){0, 0, 0, 0};
      return;
    }
    float4 v = *(const float4*)(x + i);
    int c = i & 63;
    float4 g = *(const float4*)(g1 + c);
    float4 b = *(const float4*)(b1 + c);
    float4 m = *(const float4*)(m1 + c);
    float4 vv = *(const float4*)(v1 + c);
    ushort4v r;
    float sx = g.x * rsqrtf(vv.x + BN_EPS);
    float sy = g.y * rsqrtf(vv.y + BN_EPS);
    float sz = g.z * rsqrtf(vv.z + BN_EPS);
    float sw = g.w * rsqrtf(vv.w + BN_EPS);
    r.x = f2bf(silu_f((v.x - m.x) * sx + b.x));
    r.y = f2bf(silu_f((v.y - m.y) * sy + b.y));
    r.z = f2bf(silu_f((v.z - m.z) * sz + b.z));
    r.w = f2bf(silu_f((v.w - m.w) * sw + b.w));
    *(ushort4v*)(a1bf + i) = r;
  }
}

// ---- sparse conv: 64-node tile, reg-staged gather (depth-3) + raw barrier (lgkmcnt-only).
// Block = 256 threads / 4 waves / 64 nodes. Wave w: rows (w>>1)*32..+31, cols (w&1)*32..+31.
// Staging: thread stages rows wid*16 + i*8 + sg (i=0..1), chunk q0 (16B).
// Double-buffered 8KB LDS tiles; write-side XOR swizzle phys = q0 ^ (row&7);
// read phys p = (ks*2+half) ^ (r32&7).
// Pipeline at iter k (fully unrolled; st slot = tap%3, rg slot = tap&1, buf = tap&1):
//   DSWRITE(k+1)<-st[(k+1)%3] ; GLOAD(k+3)->st[(k+3)%3] rows rg[(k+1)&1] ;
//   LDVG(k+4)->rg[k&1] (ONE nt load from fused rows[]) ; WLOAD(k+1) ;
//   COMPUTE(k) ; s_waitcnt lgkmcnt(0); s_barrier   (vmcnt NOT drained)
// GLOAD rides 2 full iterations before consumption -> ~2x latency tolerance vs R10.
// MODE 0: epilogue = +bias, FiLM, bn2+silu -> bf16 a2 (block 0 zeroes a2 row N)
// MODE 1: epilogue = +bias + residual x (nt) -> f32 out (nt)
template <int MODE>
__global__ __launch_bounds__(256, 4) void conv_k(
    const unsigned short* __restrict__ act, const int* __restrict__ rows,
    const unsigned short* __restrict__ Wp,
    const float* __restrict__ bias,
    const float* __restrict__ scale_eff, const float* __restrict__ shift,
    const int* __restrict__ bidx,
    const float* __restrict__ g2, const float* __restrict__ b2,
    const float* __restrict__ m2, const float* __restrict__ v2,
    const float* __restrict__ xres,
    unsigned short* __restrict__ out_bf, float* __restrict__ out_f, int N) {
  __shared__ unsigned short lds[2][64 * 64];

  if (MODE == 0 && blockIdx.x == 0 && threadIdx.x < 64) {
    out_bf[(size_t)N * 64 + threadIdx.x] = 0;  // zero row for conv2's invalid taps
  }
  const int tid = threadIdx.x;
  const int lane = tid & 63;
  const int wid = tid >> 6;
  const int half = lane >> 5;   // 0/1
  const int r32 = lane & 31;
  const int n0 = blockIdx.x * 64;

  const int q0 = lane & 7;      // chunk this lane stages
  const int sg = lane >> 3;     // row-subgroup 0..7
  const int RH = wid >> 1;
  const int cb = wid & 1;

  f32x16 acc;
#pragma unroll
  for (int i = 0; i < 16; ++i) acc[i] = 0.f;

  int rgA[2], rgB[2];               // gather rows, tap-parity slots
  short8 st0[2], st1[2], st2[2];    // staged row chunks, slot = tap%3
  short8 wrA[4], wrB[4];            // W fragments, tap-parity

  // thread's staged rows: rows(i) = wid*16 + i*8 + sg  (i=0..1); ONE nt load each
#define LDVG(kk, rg) do { \
    _Pragma("unroll") \
    for (int i = 0; i < 2; ++i) { \
      int node = min(n0 + wid * 16 + i * 8 + sg, N - 1); \
      rg[i] = __builtin_nontemporal_load(rows + (size_t)(kk) * N + node); \
    } } while (0)

#define GLOAD(st, rg) do { \
    _Pragma("unroll") \
    for (int i = 0; i < 2; ++i) \
      st[i] = *(const short8*)(act + (size_t)rg[i] * 64 + q0 * 8); \
  } while (0)

  // phys chunk = q0 ^ (row&7) = q0 ^ sg
#define DSWRITE(buf, st) do { \
    _Pragma("unroll") \
    for (int i = 0; i < 2; ++i) \
      *(short8*)(&lds[buf][(wid * 16 + i * 8 + sg) * 64 + (q0 ^ sg) * 8]) = st[i]; \
  } while (0)

#define WLOAD(kk, wr) do { \
    _Pragma("unroll") \
    for (int ks = 0; ks < 4; ++ks) \
      wr[ks] = ((const short8*)Wp)[((size_t)(kk) * 8 + ks * 2 + cb) * 64 + lane]; \
  } while (0)

  // read phys p = (ks*2 + half) ^ (row&7); row&7 == r32&7
#define COMPUTE(buf, wr) do { \
    _Pragma("unroll") \
    for (int ks = 0; ks < 4; ++ks) { \
      int p = (ks * 2 + half) ^ (r32 & 7); \
      short8 av = *(const short8*)(&lds[buf][(RH * 32 + r32) * 64] + p * 8); \
      acc = __builtin_amdgcn_mfma_f32_32x32x16_bf16(av, wr[ks], acc, 0, 0, 0); \
    } } while (0)

#define BARRIER() do { \
    asm volatile("s_waitcnt lgkmcnt(0)" ::: "memory"); \
    __builtin_amdgcn_s_barrier(); \
  } while (0)

  // prologue: st0<-tap0, st1<-tap1, st2<-tap2; rgB<-rows(3); wrA<-W(0)
  LDVG(0, rgA);
  GLOAD(st0, rgA);
  LDVG(1, rgB);
  GLOAD(st1, rgB);
  LDVG(2, rgA);
  GLOAD(st2, rgA);
  LDVG(3, rgB);
  WLOAD(0, wrA);
  DSWRITE(0, st0);        // compiler inserts counted vmcnt for st0 here
  BARRIER();

#pragma unroll
  for (int k = 0; k < KOFF; ++k) {
    if (k + 1 < KOFF) {          // DSWRITE(k+1) <- st[(k+1)%3] into buf (k+1)&1
      const int s = (k + 1) % 3;
      if (s == 0)      DSWRITE((k + 1) & 1, st0);
      else if (s == 1) DSWRITE((k + 1) & 1, st1);
      else             DSWRITE((k + 1) & 1, st2);
    }
    if (k + 3 < KOFF) {          // GLOAD(k+3) -> st[(k+3)%3], rows in rg[(k+1)&1]
      const int s = (k + 3) % 3;
      if ((k + 1) & 1) {
        if (s == 0) GLOAD(st0, rgB); else if (s == 1) GLOAD(st1, rgB); else GLOAD(st2, rgB);
      } else {
        if (s == 0) GLOAD(st0, rgA); else if (s == 1) GLOAD(st1, rgA); else GLOAD(st2, rgA);
      }
    }
    if (k + 4 < KOFF) {          // LDVG(k+4) -> rg[k&1]
      if (k & 1) LDVG(k + 4, rgB); else LDVG(k + 4, rgA);
    }
    if (k + 1 < KOFF) {
      if ((k + 1) & 1) WLOAD(k + 1, wrB); else WLOAD(k + 1, wrA);
    }
    if (k & 1) COMPUTE(1, wrB); else COMPUTE(0, wrA);
    if (k + 1 < KOFF) BARRIER();
  }
#undef LDVG
#undef GLOAD
#undef DSWRITE
#undef WLOAD
#undef COMPUTE
#undef BARRIER

  // D frag: col = cb*32 + r32, row = RH*32 + (r&3) + 8*(r>>2) + 4*half
  if (MODE == 0) {
    const int c = cb * 32 + r32;
    float bb = bias[c];
    float s2v = g2[c] * rsqrtf(v2[c] + BN_EPS);
    float o2v = b2[c] - m2[c] * s2v;
#pragma unroll
    for (int r = 0; r < 16; ++r) {
      int rowD = (r & 3) + 8 * (r >> 2) + 4 * half;
      int n = n0 + RH * 32 + rowD;
      if (n < N) {
        int bi = bidx[n];
        float h = acc[r] + bb;
        h = scale_eff[bi * 64 + c] * h + shift[bi * 64 + c];
        float z = h * s2v + o2v;
        out_bf[(size_t)n * 64 + c] = f2bf(silu_f(z));
      }
    }
  } else {
    const int c = cb * 32 + r32;
    float bb = bias[c];
#pragma unroll
    for (int r = 0; r < 16; ++r) {
      int rowD = (r & 3) + 8 * (r >> 2) + 4 * half;
      int n = n0 + RH * 32 + rowD;
      if (n < N) {
        float xr = __builtin_nontemporal_load(xres + (size_t)n * 64 + c);
        __builtin_nontemporal_store(acc[r] + bb + xr, out_f + (size_t)n * 64 + c);
      }
    }
  }
}

extern "C" void kernel_launch(void* const* d_in, const int* in_sizes, int n_in,
                              void* d_out, int out_size, void* d_ws, size_t ws_size,
                              hipStream_t stream) {
  const float* x    = (const float*)d_in[0];
  const float* t    = (const float*)d_in[1];
  const int*   b    = (const int*)d_in[2];
  const int*   kidx = (const int*)d_in[3];
  const int*   kval = (const int*)d_in[4];
  const float* bn1g = (const float*)d_in[5];
  const float* bn1b = (const float*)d_in[6];
  const float* bn1m = (const float*)d_in[7];
  const float* bn1v = (const float*)d_in[8];
  const float* W1   = (const float*)d_in[9];
  const float* b1c  = (const float*)d_in[10];
  const float* bn2g = (const float*)d_in[11];
  const float* bn2b = (const float*)d_in[12];
  const float* bn2m = (const float*)d_in[13];
  const float* bn2v = (const float*)d_in[14];
  const float* W2   = (const float*)d_in[15];
  const float* b2c  = (const float*)d_in[16];
  const float* Wt   = (const float*)d_in[17];
  const float* bt   = (const float*)d_in[18];
  float* out = (float*)d_out;

  const int N = in_sizes[2];        // 100000
  const int total = N * 64;

  // workspace layout (bytes); act buffers have N+1 rows (row N = zeros)
  char* ws = (char*)d_ws;
  size_t actB = ((size_t)(N + 1) * 64 * 2 + 255) & ~(size_t)255;
  unsigned short* a1bf = (unsigned short*)ws;
  unsigned short* a2bf = (unsigned short*)(ws + actB);
  const size_t wpackB = (size_t)KOFF * 4 * 2 * 64 * 8 * 2;  // 221184 B
  unsigned short* W1p = (unsigned short*)(ws + 2 * actB);
  unsigned short* W2p = (unsigned short*)(ws + 2 * actB + wpackB);
  float* scale_eff = (float*)(ws + 2 * actB + 2 * wpackB);
  float* shiftp    = scale_eff + 16 * 64;
  int*   rows      = (int*)(ws + 2 * actB + 2 * wpackB + 8192);

  // fused prep
  int rblk = (KOFF * N / 4 + 255) / 256;
  int bnblk = (total / 4 + 16 + 255) / 256;
  prep_all<<<rblk + 872 + bnblk, 256, 0, stream>>>(rblk, kidx, kval, rows, N,
                                                   t, Wt, bt, scale_eff, shiftp,
                                                   W1, W2, W1p, W2p,
                                                   x, bn1g, bn1b, bn1m, bn1v, a1bf, total);

  int nblk = (N + 63) / 64;
  conv_k<0><<<nblk, 256, 0, stream>>>(a1bf, rows, W1p, b1c, scale_eff,
                                      shiftp, b, bn2g, bn2b, bn2m, bn2v,
                                      nullptr, a2bf, nullptr, N);
  conv_k<1><<<nblk, 256, 0, stream>>>(a2bf, rows, W2p, b2c, nullptr, nullptr,
                                      nullptr, nullptr, nullptr, nullptr, nullptr,
                                      x, nullptr, out, N);
}